// Round 2
// baseline (543.794 us; speedup 1.0000x reference)
//
#include <hip/hip_runtime.h>

// ---------------------------------------------------------------------------
// ActorCriticNetMixtureExpert: B=16384, D=512, H=512, HV=256, A=32, E=8, HW=512
// Outputs: actions [8,16384,32] f32 | v [16384,1] f32 | w [16384,8] f32
// ---------------------------------------------------------------------------

typedef float   f32x4 __attribute__((ext_vector_type(4)));
typedef _Float16 f16;
typedef _Float16 f16x4 __attribute__((ext_vector_type(4)));
typedef _Float16 f16x8 __attribute__((ext_vector_type(8)));

typedef __attribute__((address_space(1))) unsigned int gas_u32;
typedef __attribute__((address_space(3))) unsigned int las_u32;

__device__ __forceinline__ void gl_lds16(const void* g, void* l) {
  // async 16B global->LDS; LDS dest is wave-uniform base + lane*16
  __builtin_amdgcn_global_load_lds((gas_u32*)g, (las_u32*)l, 16, 0, 0);
}

// swizzle: byte offset within a 64B LDS row, XOR by ((row>>1)&3)<<4.
// Readers (16 lanes reading same k-slice of 16 different rows) then spread
// across 8 bank groups -> 2-way aliasing (free on CDNA4).
__device__ __forceinline__ int swz(int row) { return ((row >> 1) & 3) << 4; }

// ---------------------------------------------------------------------------
// fp16 MFMA GEMM: C[M,N] = epi(A[M,K] @ B[K,N] + bias), B given as BT[N,K].
// Swapped-operand mfma -> lane holds 4 consecutive N cols (packed stores).
// EPI 0: relu -> f16 out.  EPI 1: tanh -> f32 out.
// grid = (M/BM * N/BN, E)
// ---------------------------------------------------------------------------
template<int BM, int BN, int WM, int WN, int EPI>
__global__ __launch_bounds__(256, 2) void gemm_f16_kernel(
    const f16* __restrict__ A, const f16* __restrict__ BT,
    const float* __restrict__ bias, void* __restrict__ Cv,
    const int M, const int N, const int K,
    const long long sAe, const long long sCe)
{
  constexpr int FM = WM / 16, FN = WN / 16;
  constexpr int WAVES_N = BN / WN;
  __shared__ __align__(16) char sm[(BM + BN) * 64];
  char* Ash = sm;
  char* Bsh = sm + BM * 64;

  const int tid = threadIdx.x;
  const int lane = tid & 63;
  const int wid = tid >> 6;
  const int e = blockIdx.y;
  const int ntn = N / BN;
  const int m0 = (blockIdx.x / ntn) * BM;
  const int n0 = (blockIdx.x % ntn) * BN;
  const f16* Ab = A + (size_t)sAe * e + (size_t)m0 * K;
  const f16* Bb = BT + (size_t)e * N * K + (size_t)n0 * K;
  const int wr = wid / WAVES_N, wc = wid % WAVES_N;

  f32x4 acc[FM][FN] = {};

  const int ksteps = K >> 5;
  for (int kt = 0; kt < ksteps; ++kt) {
    __syncthreads();  // previous iteration's LDS reads done
    const f16* Ak = Ab + (kt << 5);
    const f16* Bk = Bb + (kt << 5);
    // stage A tile [BM][32] f16 (pre-swizzled global source, linear LDS dest)
    for (int u = tid; u < BM * 4; u += 256) {
      int row = u >> 2;
      int kb = ((u & 3) << 4) ^ swz(row);
      gl_lds16(Ak + (size_t)row * K + (kb >> 1), Ash + u * 16);
    }
    for (int u = tid; u < BN * 4; u += 256) {
      int row = u >> 2;
      int kb = ((u & 3) << 4) ^ swz(row);
      gl_lds16(Bk + (size_t)row * K + (kb >> 1), Bsh + u * 16);
    }
    __syncthreads();  // compiler drains vmcnt before barrier

    f16x8 af[FM], bf[FN];
    const int kl = (lane >> 4) << 4;  // this lane's 16B k-slice
    #pragma unroll
    for (int fm = 0; fm < FM; ++fm) {
      int row = wr * WM + fm * 16 + (lane & 15);
      af[fm] = *(const f16x8*)(Ash + row * 64 + (kl ^ swz(row)));
    }
    #pragma unroll
    for (int fn = 0; fn < FN; ++fn) {
      int row = wc * WN + fn * 16 + (lane & 15);
      bf[fn] = *(const f16x8*)(Bsh + row * 64 + (kl ^ swz(row)));
    }
    #pragma unroll
    for (int fm = 0; fm < FM; ++fm)
      #pragma unroll
      for (int fn = 0; fn < FN; ++fn)
        acc[fm][fn] = __builtin_amdgcn_mfma_f32_16x16x32_f16(
            bf[fn], af[fm], acc[fm][fn], 0, 0, 0);
  }

  // epilogue: lane holds row = lane&15 (+16*fm), cols = (lane>>4)*4 (+16*fn)
  const int rbase = m0 + wr * WM + (lane & 15);
  const int cbase = n0 + wc * WN + ((lane >> 4) << 2);
  #pragma unroll
  for (int fm = 0; fm < FM; ++fm) {
    const int row = rbase + fm * 16;
    #pragma unroll
    for (int fn = 0; fn < FN; ++fn) {
      const int col = cbase + fn * 16;
      f32x4 v = acc[fm][fn];
      f32x4 bb = *(const f32x4*)(bias + (size_t)e * N + col);
      if constexpr (EPI == 0) {
        f16x4 h;
        #pragma unroll
        for (int r = 0; r < 4; ++r) h[r] = (f16)fmaxf(v[r] + bb[r], 0.0f);
        *(f16x4*)((f16*)Cv + (size_t)sCe * e + (size_t)row * N + col) = h;
      } else {
        f32x4 o;
        #pragma unroll
        for (int r = 0; r < 4; ++r) o[r] = tanhf(v[r] + bb[r]);
        *(f32x4*)((float*)Cv + (size_t)sCe * e + (size_t)row * N + col) = o;
      }
    }
  }
}

// ---------------------------------------------------------------------------
// High-precision gating GEMM via fp16x2 split: A = Ahi + Alo/1024,
// B = Bhi + Blo/1024; z = Ahi@Bhi + (Alo@Bhi + Ahi@Blo)/1024. Residual ~2^-22.
// mode 0: relu -> split store (Chi,Clo). mode 1: relu -> f32 store (C32).
// ---------------------------------------------------------------------------
__global__ __launch_bounds__(256, 2) void gemm_gate_kernel(
    const f16* __restrict__ Ahi, const f16* __restrict__ Alo,
    const f16* __restrict__ Bhi, const f16* __restrict__ Blo,
    const float* __restrict__ bias,
    f16* __restrict__ Chi, f16* __restrict__ Clo, float* __restrict__ C32,
    const int M, const int N, const int K, const int mode)
{
  constexpr int BM = 128, BN = 128, WM = 64, WN = 64, FM = 4, FN = 4, WAVES_N = 2;
  __shared__ __align__(16) char sm[4 * 128 * 64];
  char* AH = sm;
  char* AL = sm + 8192;
  char* BH = sm + 16384;
  char* BL = sm + 24576;

  const int tid = threadIdx.x;
  const int lane = tid & 63;
  const int wid = tid >> 6;
  const int ntn = N / BN;
  const int m0 = (blockIdx.x / ntn) * BM;
  const int n0 = (blockIdx.x % ntn) * BN;
  const int wr = wid / WAVES_N, wc = wid % WAVES_N;

  f32x4 a1[FM][FN] = {};
  f32x4 a2[FM][FN] = {};

  const int ksteps = K >> 5;
  for (int kt = 0; kt < ksteps; ++kt) {
    __syncthreads();
    const size_t ko = (size_t)(kt << 5);
    for (int u = tid; u < 512; u += 256) {
      int row = u >> 2;
      int kb = ((u & 3) << 4) ^ swz(row);
      size_t ga = (size_t)(m0 + row) * K + ko + (kb >> 1);
      size_t gb = (size_t)(n0 + row) * K + ko + (kb >> 1);
      gl_lds16(Ahi + ga, AH + u * 16);
      gl_lds16(Alo + ga, AL + u * 16);
      gl_lds16(Bhi + gb, BH + u * 16);
      gl_lds16(Blo + gb, BL + u * 16);
    }
    __syncthreads();

    f16x8 ah[FM], al[FM], bh[FN], bl[FN];
    const int kl = (lane >> 4) << 4;
    #pragma unroll
    for (int fm = 0; fm < FM; ++fm) {
      int row = wr * WM + fm * 16 + (lane & 15);
      int o = row * 64 + (kl ^ swz(row));
      ah[fm] = *(const f16x8*)(AH + o);
      al[fm] = *(const f16x8*)(AL + o);
    }
    #pragma unroll
    for (int fn = 0; fn < FN; ++fn) {
      int row = wc * WN + fn * 16 + (lane & 15);
      int o = row * 64 + (kl ^ swz(row));
      bh[fn] = *(const f16x8*)(BH + o);
      bl[fn] = *(const f16x8*)(BL + o);
    }
    #pragma unroll
    for (int fm = 0; fm < FM; ++fm)
      #pragma unroll
      for (int fn = 0; fn < FN; ++fn) {
        a1[fm][fn] = __builtin_amdgcn_mfma_f32_16x16x32_f16(bh[fn], ah[fm], a1[fm][fn], 0, 0, 0);
        a2[fm][fn] = __builtin_amdgcn_mfma_f32_16x16x32_f16(bh[fn], al[fm], a2[fm][fn], 0, 0, 0);
        a2[fm][fn] = __builtin_amdgcn_mfma_f32_16x16x32_f16(bl[fn], ah[fm], a2[fm][fn], 0, 0, 0);
      }
  }

  const int rbase = m0 + wr * WM + (lane & 15);
  const int cbase = n0 + wc * WN + ((lane >> 4) << 2);
  #pragma unroll
  for (int fm = 0; fm < FM; ++fm) {
    const int row = rbase + fm * 16;
    #pragma unroll
    for (int fn = 0; fn < FN; ++fn) {
      const int col = cbase + fn * 16;
      f32x4 bb = *(const f32x4*)(bias + col);
      if (mode == 0) {
        f16x4 h, l;
        #pragma unroll
        for (int r = 0; r < 4; ++r) {
          float u = fmaxf(a1[fm][fn][r] + a2[fm][fn][r] * 9.765625e-4f + bb[r], 0.0f);
          f16 hh = (f16)u;
          h[r] = hh;
          l[r] = (f16)((u - (float)hh) * 1024.0f);
        }
        *(f16x4*)(Chi + (size_t)row * N + col) = h;
        *(f16x4*)(Clo + (size_t)row * N + col) = l;
      } else {
        f32x4 o;
        #pragma unroll
        for (int r = 0; r < 4; ++r)
          o[r] = fmaxf(a1[fm][fn][r] + a2[fm][fn][r] * 9.765625e-4f + bb[r], 0.0f);
        *(f32x4*)(C32 + (size_t)row * N + col) = o;
      }
    }
  }
}

// ---------------------------------------------------------------------------
// x -> fp16 hi + 1024-scaled fp16 residual
// ---------------------------------------------------------------------------
__global__ __launch_bounds__(256) void cvt_x_kernel(
    const float* __restrict__ x, f16* __restrict__ xhi, f16* __restrict__ xlo)
{
  const size_t i = ((size_t)blockIdx.x * 256 + threadIdx.x) * 4;
  f32x4 v = *(const f32x4*)(x + i);
  f16x4 h, l;
  #pragma unroll
  for (int j = 0; j < 4; ++j) {
    f16 hh = (f16)v[j];
    h[j] = hh;
    l[j] = (f16)((v[j] - (float)hh) * 1024.0f);
  }
  *(f16x4*)(xhi + i) = h;
  *(f16x4*)(xlo + i) = l;
}

// ---------------------------------------------------------------------------
// Weight transpose: W[E][K][N] f32 -> WT[E][N][K] f16 (and hi/lo split variant)
// ---------------------------------------------------------------------------
__global__ __launch_bounds__(256) void transpose_f16_kernel(
    const float* __restrict__ W, f16* __restrict__ WT, const int K, const int N)
{
  __shared__ float t[32][33];
  const int e = blockIdx.z;
  const int k0 = blockIdx.x << 5, n0 = blockIdx.y << 5;
  const int tx = threadIdx.x & 31, ty = threadIdx.x >> 5;
  const float* Wp = W + (size_t)e * K * N;
  #pragma unroll
  for (int i = 0; i < 4; ++i) {
    int k = k0 + ty + i * 8, n = n0 + tx;
    if (k < K && n < N) t[ty + i * 8][tx] = Wp[(size_t)k * N + n];
  }
  __syncthreads();
  f16* Op = WT + (size_t)e * K * N;
  #pragma unroll
  for (int i = 0; i < 4; ++i) {
    int n = n0 + ty + i * 8, k = k0 + tx;
    if (n < N && k < K) Op[(size_t)n * K + k] = (f16)t[tx][ty + i * 8];
  }
}

__global__ __launch_bounds__(256) void transpose_split_kernel(
    const float* __restrict__ W, f16* __restrict__ Thi, f16* __restrict__ Tlo,
    const int K, const int N)
{
  __shared__ float t[32][33];
  const int k0 = blockIdx.x << 5, n0 = blockIdx.y << 5;
  const int tx = threadIdx.x & 31, ty = threadIdx.x >> 5;
  #pragma unroll
  for (int i = 0; i < 4; ++i) {
    int k = k0 + ty + i * 8, n = n0 + tx;
    if (k < K && n < N) t[ty + i * 8][tx] = W[(size_t)k * N + n];
  }
  __syncthreads();
  #pragma unroll
  for (int i = 0; i < 4; ++i) {
    int n = n0 + ty + i * 8, k = k0 + tx;
    if (n < N && k < K) {
      float v = t[tx][ty + i * 8];
      f16 hh = (f16)v;
      Thi[(size_t)n * K + k] = hh;
      Tlo[(size_t)n * K + k] = (f16)((v - (float)hh) * 1024.0f);
    }
  }
}

// ---------------------------------------------------------------------------
// Per-expert value head: values[e][b] = dot(G2[e][b][:256], Wv[e]) + bv[e]
// one wave per row
// ---------------------------------------------------------------------------
__global__ __launch_bounds__(256) void values_kernel(
    const f16* __restrict__ G2, const float* __restrict__ Wv,
    const float* __restrict__ bv, float* __restrict__ values, const int e0)
{
  const int tid = threadIdx.x, lane = tid & 63, wid = tid >> 6;
  const int gi = blockIdx.x * 4 + wid;
  const int el = gi >> 14;
  const int b = gi & 16383;
  const int eg = e0 + el;
  const f16* g = G2 + (((size_t)el << 14) + b) * 256 + (lane << 2);
  f16x4 gv = *(const f16x4*)g;
  const float* wv = Wv + ((size_t)eg << 8) + (lane << 2);
  float a = (float)gv[0] * wv[0] + (float)gv[1] * wv[1] +
            (float)gv[2] * wv[2] + (float)gv[3] * wv[3];
  #pragma unroll
  for (int off = 32; off >= 1; off >>= 1) a += __shfl_xor(a, off);
  if (lane == 0) values[((size_t)eg << 14) + b] = a + bv[eg];
}

// ---------------------------------------------------------------------------
// Threefry-2x32-20, key = (0, 42)  (jax.random.key(42))
// ---------------------------------------------------------------------------
__device__ __forceinline__ void threefry_0_42(unsigned x0, unsigned x1,
                                              unsigned& o0, unsigned& o1)
{
  const unsigned ks0 = 0u, ks1 = 42u, ks2 = 0x1BD11BDAu ^ 42u;
  x0 += ks0; x1 += ks1;
#define TF_R(r) { x0 += x1; x1 = (x1 << r) | (x1 >> (32 - r)); x1 ^= x0; }
  TF_R(13) TF_R(15) TF_R(26) TF_R(6)  x0 += ks1; x1 += ks2 + 1u;
  TF_R(17) TF_R(29) TF_R(16) TF_R(24) x0 += ks2; x1 += ks0 + 2u;
  TF_R(13) TF_R(15) TF_R(26) TF_R(6)  x0 += ks0; x1 += ks1 + 3u;
  TF_R(17) TF_R(29) TF_R(16) TF_R(24) x0 += ks1; x1 += ks2 + 4u;
  TF_R(13) TF_R(15) TF_R(26) TF_R(6)  x0 += ks2; x1 += ks0 + 5u;
#undef TF_R
  o0 = x0; o1 = x1;
}

// ---------------------------------------------------------------------------
// Gating tail: z = U2 @ Wwo + bwo (one wave per row, f32), softmax -> w,
// categorical(key=42) via threefry gumbel -> pis, gather v = values[pis][b].
// Bits per JAX partitionable threefry (default since 0.4.30):
//   (o0,o1) = threefry2x32(key, (hi32(idx), lo32(idx))); bits = o0 ^ o1
// ---------------------------------------------------------------------------
__global__ __launch_bounds__(256) void gating_out_kernel(
    const float* __restrict__ U2, const float* __restrict__ Wwo,
    const float* __restrict__ bwo, const float* __restrict__ values,
    float* __restrict__ w_out, float* __restrict__ v_out)
{
  __shared__ float wl[4096];  // Wwo [512][8]
  const int tid = threadIdx.x;
  for (int i = tid; i < 1024; i += 256)
    ((f32x4*)wl)[i] = ((const f32x4*)Wwo)[i];
  __syncthreads();
  const int lane = tid & 63, wid = tid >> 6;
  const int b = blockIdx.x * 4 + wid;

  const float* u = U2 + (size_t)b * 512 + lane * 8;
  f32x4 ua = *(const f32x4*)u;
  f32x4 ub = *(const f32x4*)(u + 4);
  float acc[8] = {};
  const float* wrow = wl + lane * 64;
  #pragma unroll
  for (int i = 0; i < 8; ++i) {
    float uv = (i < 4) ? ua[i] : ub[i - 4];
    #pragma unroll
    for (int ee = 0; ee < 8; ++ee) acc[ee] += uv * wrow[i * 8 + ee];
  }
  #pragma unroll
  for (int off = 32; off >= 1; off >>= 1)
    #pragma unroll
    for (int ee = 0; ee < 8; ++ee) acc[ee] += __shfl_xor(acc[ee], off);
  #pragma unroll
  for (int ee = 0; ee < 8; ++ee) acc[ee] += bwo[ee];

  // softmax pieces (all lanes identical, static indexing only)
  float zmax = acc[0];
  #pragma unroll
  for (int ee = 1; ee < 8; ++ee) zmax = fmaxf(zmax, acc[ee]);
  float s = 0.0f;
  #pragma unroll
  for (int ee = 0; ee < 8; ++ee) s += expf(acc[ee] - zmax);

  // select this lane's own z without dynamic indexing
  float t0 = (lane & 1) ? acc[1] : acc[0];
  float t1 = (lane & 1) ? acc[3] : acc[2];
  float t2 = (lane & 1) ? acc[5] : acc[4];
  float t3 = (lane & 1) ? acc[7] : acc[6];
  float s0 = (lane & 2) ? t1 : t0;
  float s1 = (lane & 2) ? t3 : t2;
  float zown = (lane & 4) ? s1 : s0;

  if (lane < 8) w_out[(size_t)b * 8 + lane] = expf(zown - zmax) / s;

  // gumbel bits: JAX partitionable threefry, counter = (0, idx), xor outputs
  unsigned idx = ((unsigned)b << 3) | (unsigned)(lane & 7);
  unsigned o0, o1;
  threefry_0_42(0u, idx, o0, o1);
  unsigned bits = o0 ^ o1;
  float f = __uint_as_float((bits >> 9) | 0x3F800000u) - 1.0f;
  f = fmaxf(f, 1.17549435e-38f);
  float g = -logf(-logf(f));
  float y = (lane < 8) ? (zown + g) : -3.0e38f;

  // argmax over lanes 0..7, first index wins on ties (jnp.argmax semantics)
  float best = __shfl(y, 0);
  int pi = 0;
  #pragma unroll
  for (int ee = 1; ee < 8; ++ee) {
    float ye = __shfl(y, ee);
    if (ye > best) { best = ye; pi = ee; }
  }
  if (lane == 0) v_out[b] = values[((size_t)pi << 14) + b];
}

// ---------------------------------------------------------------------------
// host launch
// ---------------------------------------------------------------------------
extern "C" void kernel_launch(void* const* d_in, const int* in_sizes, int n_in,
                              void* d_out, int out_size, void* d_ws, size_t ws_size,
                              hipStream_t stream) {
  (void)in_sizes; (void)n_in; (void)out_size;
  const float* x   = (const float*)d_in[0];
  const float* Wp0 = (const float*)d_in[1];
  const float* bp0 = (const float*)d_in[2];
  const float* Wp1 = (const float*)d_in[3];
  const float* bp1 = (const float*)d_in[4];
  const float* Wmu = (const float*)d_in[5];
  const float* bmu = (const float*)d_in[6];
  const float* Wv0 = (const float*)d_in[7];
  const float* bv0 = (const float*)d_in[8];
  const float* Wv1 = (const float*)d_in[9];
  const float* bv1 = (const float*)d_in[10];
  const float* Wv  = (const float*)d_in[11];
  const float* bv  = (const float*)d_in[12];
  const float* Ww0 = (const float*)d_in[13];
  const float* bw0 = (const float*)d_in[14];
  const float* Ww1 = (const float*)d_in[15];
  const float* bw1 = (const float*)d_in[16];
  const float* Wwo = (const float*)d_in[17];
  const float* bwo = (const float*)d_in[18];

  float* out_actions = (float*)d_out;                       // [8,16384,32]
  float* out_v = out_actions + (size_t)8 * 16384 * 32;      // [16384,1]
  float* out_w = out_v + 16384;                             // [16384,8]

  char* base = (char*)d_ws;
  size_t off = 0;
  auto alloc = [&](size_t bytes) -> char* {
    char* p = base + off;
    off = (off + bytes + 255) & ~(size_t)255;
    return p;
  };

  const size_t BD2 = (size_t)16384 * 512 * 2;  // 16.78 MB (one [B][512] f16)

  f16* x16    = (f16*)alloc(BD2);
  f16* xlo    = (f16*)alloc(BD2);
  f16* Wp0T   = (f16*)alloc((size_t)8 * 512 * 512 * 2);
  f16* Wp1T   = (f16*)alloc((size_t)8 * 512 * 512 * 2);
  f16* WmuT   = (f16*)alloc((size_t)8 * 32 * 512 * 2);
  f16* Wv0T   = (f16*)alloc((size_t)8 * 256 * 512 * 2);
  f16* Wv1T   = (f16*)alloc((size_t)8 * 256 * 256 * 2);
  f16* Ww0Thi = (f16*)alloc((size_t)512 * 512 * 2);
  f16* Ww0Tlo = (f16*)alloc((size_t)512 * 512 * 2);
  f16* Ww1Thi = (f16*)alloc((size_t)512 * 512 * 2);
  f16* Ww1Tlo = (f16*)alloc((size_t)512 * 512 * 2);
  float* valuesBuf = (float*)alloc((size_t)8 * 16384 * 4);

  // expert-group size chosen to fit workspace; U1/U2 alias the big buffers
  // (dead by gating time) when eg >= 2.
  size_t core = off;
  int eg = 8;
  while (eg > 1 && core + (size_t)2 * eg * BD2 > ws_size) eg >>= 1;

  f16 *BIG1, *BIG2, *U1hi, *U1lo;
  float* U2;
  if (eg >= 2) {
    BIG1 = (f16*)alloc((size_t)eg * BD2);
    BIG2 = (f16*)alloc((size_t)eg * BD2);
    U1hi = BIG1;
    U1lo = BIG1 + (size_t)16384 * 512;
    U2 = (float*)BIG2;
  } else {
    BIG1 = (f16*)alloc(BD2);
    BIG2 = (f16*)alloc(BD2);
    U1hi = (f16*)alloc(BD2);
    U1lo = (f16*)alloc(BD2);
    U2 = (float*)alloc((size_t)16384 * 512 * 4);
  }

  dim3 blk(256);
  const long long sBD = 16384LL * 512;
  const long long sBH = 16384LL * 256;

  // input conversion + weight transposes
  cvt_x_kernel<<<8192, blk, 0, stream>>>(x, x16, xlo);
  transpose_f16_kernel<<<dim3(16, 16, 8), blk, 0, stream>>>(Wp0, Wp0T, 512, 512);
  transpose_f16_kernel<<<dim3(16, 16, 8), blk, 0, stream>>>(Wp1, Wp1T, 512, 512);
  transpose_f16_kernel<<<dim3(16, 1, 8), blk, 0, stream>>>(Wmu, WmuT, 512, 32);
  transpose_f16_kernel<<<dim3(16, 8, 8), blk, 0, stream>>>(Wv0, Wv0T, 512, 256);
  transpose_f16_kernel<<<dim3(8, 8, 8), blk, 0, stream>>>(Wv1, Wv1T, 256, 256);
  transpose_split_kernel<<<dim3(16, 16, 1), blk, 0, stream>>>(Ww0, Ww0Thi, Ww0Tlo, 512, 512);
  transpose_split_kernel<<<dim3(16, 16, 1), blk, 0, stream>>>(Ww1, Ww1Thi, Ww1Tlo, 512, 512);

  // policy chain (grouped over experts)
  for (int e0 = 0; e0 < 8; e0 += eg) {
    gemm_f16_kernel<128, 128, 64, 64, 0><<<dim3(512, eg), blk, 0, stream>>>(
        x16, Wp0T + (size_t)e0 * 512 * 512, bp0 + e0 * 512, BIG1,
        16384, 512, 512, 0, sBD);
    gemm_f16_kernel<128, 128, 64, 64, 0><<<dim3(512, eg), blk, 0, stream>>>(
        BIG1, Wp1T + (size_t)e0 * 512 * 512, bp1 + e0 * 512, BIG2,
        16384, 512, 512, sBD, sBD);
    gemm_f16_kernel<128, 32, 32, 32, 1><<<dim3(128, eg), blk, 0, stream>>>(
        BIG2, WmuT + (size_t)e0 * 32 * 512, bmu + e0 * 32,
        out_actions + (size_t)e0 * 16384 * 32,
        16384, 32, 512, sBD, 16384LL * 32);
  }

  // value chain (grouped over experts)
  for (int e0 = 0; e0 < 8; e0 += eg) {
    gemm_f16_kernel<128, 128, 64, 64, 0><<<dim3(256, eg), blk, 0, stream>>>(
        x16, Wv0T + (size_t)e0 * 256 * 512, bv0 + e0 * 256, BIG1,
        16384, 256, 512, 0, sBH);
    gemm_f16_kernel<128, 128, 64, 64, 0><<<dim3(256, eg), blk, 0, stream>>>(
        BIG1, Wv1T + (size_t)e0 * 256 * 256, bv1 + e0 * 256, BIG2,
        16384, 256, 256, sBH, sBH);
    values_kernel<<<eg * 4096, blk, 0, stream>>>((const f16*)BIG2, Wv, bv, valuesBuf, e0);
  }

  // gating network (fp16x2 split, ~f32 accuracy), then softmax/sample/gather
  gemm_gate_kernel<<<dim3(512, 1), blk, 0, stream>>>(
      x16, xlo, Ww0Thi, Ww0Tlo, bw0, U1hi, U1lo, nullptr, 16384, 512, 512, 0);
  gemm_gate_kernel<<<dim3(512, 1), blk, 0, stream>>>(
      U1hi, U1lo, Ww1Thi, Ww1Tlo, bw1, nullptr, nullptr, U2, 16384, 512, 512, 1);
  gating_out_kernel<<<4096, blk, 0, stream>>>(U2, Wwo, bwo, valuesBuf, out_w, out_v);
}

// Round 3
// 466.698 us; speedup vs baseline: 1.1652x; 1.1652x over previous
//
#include <hip/hip_runtime.h>

// ---------------------------------------------------------------------------
// ActorCriticNetMixtureExpert: B=16384, D=512, H=512, HV=256, A=32, E=8, HW=512
// Outputs: actions [8,16384,32] f32 | v [16384,1] f32 | w [16384,8] f32
// ---------------------------------------------------------------------------

typedef float   f32x4 __attribute__((ext_vector_type(4)));
typedef _Float16 f16;
typedef _Float16 f16x4 __attribute__((ext_vector_type(4)));
typedef _Float16 f16x8 __attribute__((ext_vector_type(8)));

typedef __attribute__((address_space(1))) unsigned int gas_u32;
typedef __attribute__((address_space(3))) unsigned int las_u32;

__device__ __forceinline__ void gl_lds16(const void* g, void* l) {
  // async 16B global->LDS; LDS dest is wave-uniform base + lane*16
  __builtin_amdgcn_global_load_lds((gas_u32*)g, (las_u32*)l, 16, 0, 0);
}

// bijective XCD-chunked swizzle (m204): orig block b -> logical L such that
// XCD (b%8) executes a contiguous logical chunk.
__device__ __forceinline__ int xcd_swz(int b, int G) {
  int q = G >> 3, r = G & 7;
  int x = b & 7, y = b >> 3;
  return (x < r ? x * (q + 1) : r * (q + 1) + (x - r) * q) + y;
}

// ---------------------------------------------------------------------------
// fp16 MFMA GEMM, BK=64, expert-concat columns.
// C[e][M][Nreal] = epi(A[e][M][K] @ B[K][*] + bias), B given as BT[nv][K]
// (contiguous across experts), bias contiguous [E*Nreal].
// Virtual col nv0 -> e = nv0>>eShift, col0 = nv0 & (Nreal-1).
// Block decomposition of logical L: nIn (fastest) -> m -> eOuter.
//  - shared-A layers (L1): nInner = all n-tiles, eOuter = 1 (A reuse x nInner)
//  - per-expert layers:    nInner = Nreal/BN, eOuter = experts
// LDS rows are 128B, XOR-swizzled by ((row&7)<<4) (G4 bank-conflict fix).
// EPI 0: relu -> f16 out.  EPI 1: tanh -> f32 out.
// ---------------------------------------------------------------------------
template<int BM, int BN, int WM, int WN, int EPI>
__global__ __launch_bounds__(256, 2) void gemm2_kernel(
    const f16* __restrict__ A, const f16* __restrict__ BT,
    const float* __restrict__ bias, void* __restrict__ Cv,
    const int K, const long long sAe, const long long sCe,
    const int mT, const int nInner, const int eShift)
{
  constexpr int FM = WM / 16, FN = WN / 16;
  constexpr int WAVES_N = BN / WN;
  __shared__ __align__(16) char sm[(BM + BN) * 128];
  char* Ash = sm;
  char* Bsh = sm + BM * 128;

  const int tid = threadIdx.x;
  const int lane = tid & 63;
  const int wid = tid >> 6;

  const int L = xcd_swz(blockIdx.x, gridDim.x);
  const int nIn = L % nInner;
  const int m   = (L / nInner) % mT;
  const int eo  = L / (nInner * mT);
  const int Nreal = 1 << eShift;
  const int nv0 = (eo * nInner + nIn) * BN;
  const int e = nv0 >> eShift;
  const int col0 = nv0 & (Nreal - 1);
  const int m0 = m * BM;

  const f16* Ab = A + (size_t)sAe * e + (size_t)m0 * K;
  const f16* Bb = BT + (size_t)nv0 * K;
  const int wr = wid / WAVES_N, wc = wid % WAVES_N;

  f32x4 acc[FM][FN] = {};

  const int ksteps = K >> 6;
  for (int kt = 0; kt < ksteps; ++kt) {
    __syncthreads();  // previous iteration's LDS reads done
    const f16* Ak = Ab + (kt << 6);
    const f16* Bk = Bb + (kt << 6);
    // stage A tile [BM][64] f16 (pre-swizzled global source, linear LDS dest)
    for (int u = tid; u < BM * 8; u += 256) {
      int row = u >> 3;
      int kb = ((u & 7) << 4) ^ ((row & 7) << 4);
      gl_lds16(Ak + (size_t)row * K + (kb >> 1), Ash + u * 16);
    }
    for (int u = tid; u < BN * 8; u += 256) {
      int row = u >> 3;
      int kb = ((u & 7) << 4) ^ ((row & 7) << 4);
      gl_lds16(Bk + (size_t)row * K + (kb >> 1), Bsh + u * 16);
    }
    __syncthreads();  // compiler drains vmcnt before barrier

    f16x8 af[FM][2], bf[FN][2];
    const int kl = (lane >> 4) << 4;  // this lane's 16B k-slice within 32-K
    #pragma unroll
    for (int fm = 0; fm < FM; ++fm) {
      int row = wr * WM + fm * 16 + (lane & 15);
      int sw = (row & 7) << 4;
      af[fm][0] = *(const f16x8*)(Ash + row * 128 + (kl ^ sw));
      af[fm][1] = *(const f16x8*)(Ash + row * 128 + ((64 + kl) ^ sw));
    }
    #pragma unroll
    for (int fn = 0; fn < FN; ++fn) {
      int row = wc * WN + fn * 16 + (lane & 15);
      int sw = (row & 7) << 4;
      bf[fn][0] = *(const f16x8*)(Bsh + row * 128 + (kl ^ sw));
      bf[fn][1] = *(const f16x8*)(Bsh + row * 128 + ((64 + kl) ^ sw));
    }
    #pragma unroll
    for (int fm = 0; fm < FM; ++fm)
      #pragma unroll
      for (int fn = 0; fn < FN; ++fn) {
        acc[fm][fn] = __builtin_amdgcn_mfma_f32_16x16x32_f16(
            bf[fn][0], af[fm][0], acc[fm][fn], 0, 0, 0);
        acc[fm][fn] = __builtin_amdgcn_mfma_f32_16x16x32_f16(
            bf[fn][1], af[fm][1], acc[fm][fn], 0, 0, 0);
      }
  }

  // epilogue: lane holds row = lane&15 (+16*fm), cols = (lane>>4)*4 (+16*fn)
  const int rbase = m0 + wr * WM + (lane & 15);
  const int cb = wc * WN + ((lane >> 4) << 2);
  #pragma unroll
  for (int fm = 0; fm < FM; ++fm) {
    const int row = rbase + fm * 16;
    #pragma unroll
    for (int fn = 0; fn < FN; ++fn) {
      const int bcol = cb + fn * 16;
      f32x4 v = acc[fm][fn];
      f32x4 bb = *(const f32x4*)(bias + nv0 + bcol);
      if constexpr (EPI == 0) {
        f16x4 h;
        #pragma unroll
        for (int r = 0; r < 4; ++r) h[r] = (f16)fmaxf(v[r] + bb[r], 0.0f);
        *(f16x4*)((f16*)Cv + (size_t)sCe * e + (size_t)row * Nreal + col0 + bcol) = h;
      } else {
        f32x4 o;
        #pragma unroll
        for (int r = 0; r < 4; ++r) o[r] = tanhf(v[r] + bb[r]);
        *(f32x4*)((float*)Cv + (size_t)sCe * e + (size_t)row * Nreal + col0 + bcol) = o;
      }
    }
  }
}

// ---------------------------------------------------------------------------
// High-precision gating GEMM via fp16x2 split: A = Ahi + Alo/1024,
// B = Bhi + Blo/1024; z = Ahi@Bhi + (Alo@Bhi + Ahi@Blo)/1024. Residual ~2^-22.
// mode 0: relu -> split store (Chi,Clo). mode 1: relu -> f32 store (C32).
// ---------------------------------------------------------------------------
__device__ __forceinline__ int swz32(int row) { return ((row >> 1) & 3) << 4; }

__global__ __launch_bounds__(256, 2) void gemm_gate_kernel(
    const f16* __restrict__ Ahi, const f16* __restrict__ Alo,
    const f16* __restrict__ Bhi, const f16* __restrict__ Blo,
    const float* __restrict__ bias,
    f16* __restrict__ Chi, f16* __restrict__ Clo, float* __restrict__ C32,
    const int M, const int N, const int K, const int mode)
{
  constexpr int BM = 128, BN = 128, WM = 64, WN = 64, FM = 4, FN = 4, WAVES_N = 2;
  __shared__ __align__(16) char sm[4 * 128 * 64];
  char* AH = sm;
  char* AL = sm + 8192;
  char* BH = sm + 16384;
  char* BL = sm + 24576;

  const int tid = threadIdx.x;
  const int lane = tid & 63;
  const int wid = tid >> 6;
  const int L = xcd_swz(blockIdx.x, gridDim.x);
  const int ntn = N / BN;
  const int m0 = (L / ntn) * BM;
  const int n0 = (L % ntn) * BN;
  const int wr = wid / WAVES_N, wc = wid % WAVES_N;

  f32x4 a1[FM][FN] = {};
  f32x4 a2[FM][FN] = {};

  const int ksteps = K >> 5;
  for (int kt = 0; kt < ksteps; ++kt) {
    __syncthreads();
    const size_t ko = (size_t)(kt << 5);
    for (int u = tid; u < 512; u += 256) {
      int row = u >> 2;
      int kb = ((u & 3) << 4) ^ swz32(row);
      size_t ga = (size_t)(m0 + row) * K + ko + (kb >> 1);
      size_t gb = (size_t)(n0 + row) * K + ko + (kb >> 1);
      gl_lds16(Ahi + ga, AH + u * 16);
      gl_lds16(Alo + ga, AL + u * 16);
      gl_lds16(Bhi + gb, BH + u * 16);
      gl_lds16(Blo + gb, BL + u * 16);
    }
    __syncthreads();

    f16x8 ah[FM], al[FM], bh[FN], bl[FN];
    const int kl = (lane >> 4) << 4;
    #pragma unroll
    for (int fm = 0; fm < FM; ++fm) {
      int row = wr * WM + fm * 16 + (lane & 15);
      int o = row * 64 + (kl ^ swz32(row));
      ah[fm] = *(const f16x8*)(AH + o);
      al[fm] = *(const f16x8*)(AL + o);
    }
    #pragma unroll
    for (int fn = 0; fn < FN; ++fn) {
      int row = wc * WN + fn * 16 + (lane & 15);
      int o = row * 64 + (kl ^ swz32(row));
      bh[fn] = *(const f16x8*)(BH + o);
      bl[fn] = *(const f16x8*)(BL + o);
    }
    #pragma unroll
    for (int fm = 0; fm < FM; ++fm)
      #pragma unroll
      for (int fn = 0; fn < FN; ++fn) {
        a1[fm][fn] = __builtin_amdgcn_mfma_f32_16x16x32_f16(bh[fn], ah[fm], a1[fm][fn], 0, 0, 0);
        a2[fm][fn] = __builtin_amdgcn_mfma_f32_16x16x32_f16(bh[fn], al[fm], a2[fm][fn], 0, 0, 0);
        a2[fm][fn] = __builtin_amdgcn_mfma_f32_16x16x32_f16(bl[fn], ah[fm], a2[fm][fn], 0, 0, 0);
      }
  }

  const int rbase = m0 + wr * WM + (lane & 15);
  const int cbase = n0 + wc * WN + ((lane >> 4) << 2);
  #pragma unroll
  for (int fm = 0; fm < FM; ++fm) {
    const int row = rbase + fm * 16;
    #pragma unroll
    for (int fn = 0; fn < FN; ++fn) {
      const int col = cbase + fn * 16;
      f32x4 bb = *(const f32x4*)(bias + col);
      if (mode == 0) {
        f16x4 h, l;
        #pragma unroll
        for (int r = 0; r < 4; ++r) {
          float u = fmaxf(a1[fm][fn][r] + a2[fm][fn][r] * 9.765625e-4f + bb[r], 0.0f);
          f16 hh = (f16)u;
          h[r] = hh;
          l[r] = (f16)((u - (float)hh) * 1024.0f);
        }
        *(f16x4*)(Chi + (size_t)row * N + col) = h;
        *(f16x4*)(Clo + (size_t)row * N + col) = l;
      } else {
        f32x4 o;
        #pragma unroll
        for (int r = 0; r < 4; ++r)
          o[r] = fmaxf(a1[fm][fn][r] + a2[fm][fn][r] * 9.765625e-4f + bb[r], 0.0f);
        *(f32x4*)(C32 + (size_t)row * N + col) = o;
      }
    }
  }
}

// ---------------------------------------------------------------------------
// x -> fp16 hi + 1024-scaled fp16 residual
// ---------------------------------------------------------------------------
__global__ __launch_bounds__(256) void cvt_x_kernel(
    const float* __restrict__ x, f16* __restrict__ xhi, f16* __restrict__ xlo)
{
  const size_t i = ((size_t)blockIdx.x * 256 + threadIdx.x) * 4;
  f32x4 v = *(const f32x4*)(x + i);
  f16x4 h, l;
  #pragma unroll
  for (int j = 0; j < 4; ++j) {
    f16 hh = (f16)v[j];
    h[j] = hh;
    l[j] = (f16)((v[j] - (float)hh) * 1024.0f);
  }
  *(f16x4*)(xhi + i) = h;
  *(f16x4*)(xlo + i) = l;
}

// ---------------------------------------------------------------------------
// Weight transpose: W[E][K][N] f32 -> WT[E][N][K] f16 (and hi/lo split variant)
// ---------------------------------------------------------------------------
__global__ __launch_bounds__(256) void transpose_f16_kernel(
    const float* __restrict__ W, f16* __restrict__ WT, const int K, const int N)
{
  __shared__ float t[32][33];
  const int e = blockIdx.z;
  const int k0 = blockIdx.x << 5, n0 = blockIdx.y << 5;
  const int tx = threadIdx.x & 31, ty = threadIdx.x >> 5;
  const float* Wp = W + (size_t)e * K * N;
  #pragma unroll
  for (int i = 0; i < 4; ++i) {
    int k = k0 + ty + i * 8, n = n0 + tx;
    if (k < K && n < N) t[ty + i * 8][tx] = Wp[(size_t)k * N + n];
  }
  __syncthreads();
  f16* Op = WT + (size_t)e * K * N;
  #pragma unroll
  for (int i = 0; i < 4; ++i) {
    int n = n0 + ty + i * 8, k = k0 + tx;
    if (n < N && k < K) Op[(size_t)n * K + k] = (f16)t[tx][ty + i * 8];
  }
}

__global__ __launch_bounds__(256) void transpose_split_kernel(
    const float* __restrict__ W, f16* __restrict__ Thi, f16* __restrict__ Tlo,
    const int K, const int N)
{
  __shared__ float t[32][33];
  const int k0 = blockIdx.x << 5, n0 = blockIdx.y << 5;
  const int tx = threadIdx.x & 31, ty = threadIdx.x >> 5;
  #pragma unroll
  for (int i = 0; i < 4; ++i) {
    int k = k0 + ty + i * 8, n = n0 + tx;
    if (k < K && n < N) t[ty + i * 8][tx] = W[(size_t)k * N + n];
  }
  __syncthreads();
  #pragma unroll
  for (int i = 0; i < 4; ++i) {
    int n = n0 + ty + i * 8, k = k0 + tx;
    if (n < N && k < K) {
      float v = t[tx][ty + i * 8];
      f16 hh = (f16)v;
      Thi[(size_t)n * K + k] = hh;
      Tlo[(size_t)n * K + k] = (f16)((v - (float)hh) * 1024.0f);
    }
  }
}

// ---------------------------------------------------------------------------
// Per-expert value head: values[e][b] = dot(G2[e][b][:256], Wv[e]) + bv[e]
// one wave per row
// ---------------------------------------------------------------------------
__global__ __launch_bounds__(256) void values_kernel(
    const f16* __restrict__ G2, const float* __restrict__ Wv,
    const float* __restrict__ bv, float* __restrict__ values, const int e0)
{
  const int tid = threadIdx.x, lane = tid & 63, wid = tid >> 6;
  const int gi = blockIdx.x * 4 + wid;
  const int el = gi >> 14;
  const int b = gi & 16383;
  const int eg = e0 + el;
  const f16* g = G2 + (((size_t)el << 14) + b) * 256 + (lane << 2);
  f16x4 gv = *(const f16x4*)g;
  const float* wv = Wv + ((size_t)eg << 8) + (lane << 2);
  float a = (float)gv[0] * wv[0] + (float)gv[1] * wv[1] +
            (float)gv[2] * wv[2] + (float)gv[3] * wv[3];
  #pragma unroll
  for (int off = 32; off >= 1; off >>= 1) a += __shfl_xor(a, off);
  if (lane == 0) values[((size_t)eg << 14) + b] = a + bv[eg];
}

// ---------------------------------------------------------------------------
// Threefry-2x32-20, key = (0, 42)  (jax.random.key(42))
// ---------------------------------------------------------------------------
__device__ __forceinline__ void threefry_0_42(unsigned x0, unsigned x1,
                                              unsigned& o0, unsigned& o1)
{
  const unsigned ks0 = 0u, ks1 = 42u, ks2 = 0x1BD11BDAu ^ 42u;
  x0 += ks0; x1 += ks1;
#define TF_R(r) { x0 += x1; x1 = (x1 << r) | (x1 >> (32 - r)); x1 ^= x0; }
  TF_R(13) TF_R(15) TF_R(26) TF_R(6)  x0 += ks1; x1 += ks2 + 1u;
  TF_R(17) TF_R(29) TF_R(16) TF_R(24) x0 += ks2; x1 += ks0 + 2u;
  TF_R(13) TF_R(15) TF_R(26) TF_R(6)  x0 += ks0; x1 += ks1 + 3u;
  TF_R(17) TF_R(29) TF_R(16) TF_R(24) x0 += ks1; x1 += ks2 + 4u;
  TF_R(13) TF_R(15) TF_R(26) TF_R(6)  x0 += ks2; x1 += ks0 + 5u;
#undef TF_R
  o0 = x0; o1 = x1;
}

// ---------------------------------------------------------------------------
// Gating tail: z = U2 @ Wwo + bwo (one wave per row, f32), softmax -> w,
// categorical(key=42) via threefry gumbel -> pis, gather v = values[pis][b].
// Bits per JAX partitionable threefry: counter (0, idx), bits = o0 ^ o1.
// ---------------------------------------------------------------------------
__global__ __launch_bounds__(256) void gating_out_kernel(
    const float* __restrict__ U2, const float* __restrict__ Wwo,
    const float* __restrict__ bwo, const float* __restrict__ values,
    float* __restrict__ w_out, float* __restrict__ v_out)
{
  __shared__ float wl[4096];  // Wwo [512][8]
  const int tid = threadIdx.x;
  for (int i = tid; i < 1024; i += 256)
    ((f32x4*)wl)[i] = ((const f32x4*)Wwo)[i];
  __syncthreads();
  const int lane = tid & 63, wid = tid >> 6;
  const int b = blockIdx.x * 4 + wid;

  const float* u = U2 + (size_t)b * 512 + lane * 8;
  f32x4 ua = *(const f32x4*)u;
  f32x4 ub = *(const f32x4*)(u + 4);
  float acc[8] = {};
  const float* wrow = wl + lane * 64;
  #pragma unroll
  for (int i = 0; i < 8; ++i) {
    float uv = (i < 4) ? ua[i] : ub[i - 4];
    #pragma unroll
    for (int ee = 0; ee < 8; ++ee) acc[ee] += uv * wrow[i * 8 + ee];
  }
  #pragma unroll
  for (int off = 32; off >= 1; off >>= 1)
    #pragma unroll
    for (int ee = 0; ee < 8; ++ee) acc[ee] += __shfl_xor(acc[ee], off);
  #pragma unroll
  for (int ee = 0; ee < 8; ++ee) acc[ee] += bwo[ee];

  float zmax = acc[0];
  #pragma unroll
  for (int ee = 1; ee < 8; ++ee) zmax = fmaxf(zmax, acc[ee]);
  float s = 0.0f;
  #pragma unroll
  for (int ee = 0; ee < 8; ++ee) s += expf(acc[ee] - zmax);

  float t0 = (lane & 1) ? acc[1] : acc[0];
  float t1 = (lane & 1) ? acc[3] : acc[2];
  float t2 = (lane & 1) ? acc[5] : acc[4];
  float t3 = (lane & 1) ? acc[7] : acc[6];
  float s0 = (lane & 2) ? t1 : t0;
  float s1 = (lane & 2) ? t3 : t2;
  float zown = (lane & 4) ? s1 : s0;

  if (lane < 8) w_out[(size_t)b * 8 + lane] = expf(zown - zmax) / s;

  unsigned idx = ((unsigned)b << 3) | (unsigned)(lane & 7);
  unsigned o0, o1;
  threefry_0_42(0u, idx, o0, o1);
  unsigned bits = o0 ^ o1;
  float f = __uint_as_float((bits >> 9) | 0x3F800000u) - 1.0f;
  f = fmaxf(f, 1.17549435e-38f);
  float g = -logf(-logf(f));
  float y = (lane < 8) ? (zown + g) : -3.0e38f;

  float best = __shfl(y, 0);
  int pi = 0;
  #pragma unroll
  for (int ee = 1; ee < 8; ++ee) {
    float ye = __shfl(y, ee);
    if (ye > best) { best = ye; pi = ee; }
  }
  if (lane == 0) v_out[b] = values[((size_t)pi << 14) + b];
}

// ---------------------------------------------------------------------------
// host launch
// ---------------------------------------------------------------------------
extern "C" void kernel_launch(void* const* d_in, const int* in_sizes, int n_in,
                              void* d_out, int out_size, void* d_ws, size_t ws_size,
                              hipStream_t stream) {
  (void)in_sizes; (void)n_in; (void)out_size;
  const float* x   = (const float*)d_in[0];
  const float* Wp0 = (const float*)d_in[1];
  const float* bp0 = (const float*)d_in[2];
  const float* Wp1 = (const float*)d_in[3];
  const float* bp1 = (const float*)d_in[4];
  const float* Wmu = (const float*)d_in[5];
  const float* bmu = (const float*)d_in[6];
  const float* Wv0 = (const float*)d_in[7];
  const float* bv0 = (const float*)d_in[8];
  const float* Wv1 = (const float*)d_in[9];
  const float* bv1 = (const float*)d_in[10];
  const float* Wv  = (const float*)d_in[11];
  const float* bv  = (const float*)d_in[12];
  const float* Ww0 = (const float*)d_in[13];
  const float* bw0 = (const float*)d_in[14];
  const float* Ww1 = (const float*)d_in[15];
  const float* bw1 = (const float*)d_in[16];
  const float* Wwo = (const float*)d_in[17];
  const float* bwo = (const float*)d_in[18];

  float* out_actions = (float*)d_out;                       // [8,16384,32]
  float* out_v = out_actions + (size_t)8 * 16384 * 32;      // [16384,1]
  float* out_w = out_v + 16384;                             // [16384,8]

  char* base = (char*)d_ws;
  size_t off = 0;
  auto alloc = [&](size_t bytes) -> char* {
    char* p = base + off;
    off = (off + bytes + 255) & ~(size_t)255;
    return p;
  };

  const size_t BD2 = (size_t)16384 * 512 * 2;  // 16.78 MB (one [B][512] f16)
  const size_t BH2 = (size_t)16384 * 256 * 2;  // 8.39 MB (one [B][256] f16)

  f16* x16    = (f16*)alloc(BD2);
  f16* xlo    = (f16*)alloc(BD2);
  f16* Wp0T   = (f16*)alloc((size_t)8 * 512 * 512 * 2);
  f16* Wp1T   = (f16*)alloc((size_t)8 * 512 * 512 * 2);
  f16* WmuT   = (f16*)alloc((size_t)8 * 32 * 512 * 2);
  f16* Wv0T   = (f16*)alloc((size_t)8 * 256 * 512 * 2);
  f16* Wv1T   = (f16*)alloc((size_t)8 * 256 * 256 * 2);
  f16* Ww0Thi = (f16*)alloc((size_t)512 * 512 * 2);
  f16* Ww0Tlo = (f16*)alloc((size_t)512 * 512 * 2);
  f16* Ww1Thi = (f16*)alloc((size_t)512 * 512 * 2);
  f16* Ww1Tlo = (f16*)alloc((size_t)512 * 512 * 2);
  float* valuesBuf = (float*)alloc((size_t)8 * 16384 * 4);

  // expert-group size chosen to fit workspace
  size_t core = off;
  int eg = 8;
  while (eg > 1 && core + (size_t)2 * eg * BD2 > ws_size) eg >>= 1;
  const int eg_v = (2 * eg > 8) ? 8 : 2 * eg;  // value buffers are half size

  f16 *BIG1, *BIG2, *U1hi, *U1lo;
  float* U2;
  if (eg >= 2) {
    BIG1 = (f16*)alloc((size_t)eg * BD2);
    BIG2 = (f16*)alloc((size_t)eg * BD2);
    U1hi = BIG1;
    U1lo = BIG1 + (size_t)16384 * 512;
    U2 = (float*)BIG2;
  } else {
    BIG1 = (f16*)alloc(BD2);
    BIG2 = (f16*)alloc(BD2);
    U1hi = (f16*)alloc(BD2);
    U1lo = (f16*)alloc(BD2);
    U2 = (float*)alloc((size_t)16384 * 512 * 4);
  }
  // value-chain views over the same arena (policy data dead by then)
  f16* VB1 = BIG1;
  f16* VB2 = (f16*)((char*)BIG1 + (size_t)eg_v * BH2);

  dim3 blk(256);
  const long long sBD = 16384LL * 512;
  const long long sBH = 16384LL * 256;

  // input conversion + weight transposes
  cvt_x_kernel<<<8192, blk, 0, stream>>>(x, x16, xlo);
  transpose_f16_kernel<<<dim3(16, 16, 8), blk, 0, stream>>>(Wp0, Wp0T, 512, 512);
  transpose_f16_kernel<<<dim3(16, 16, 8), blk, 0, stream>>>(Wp1, Wp1T, 512, 512);
  transpose_f16_kernel<<<dim3(16, 1, 8), blk, 0, stream>>>(Wmu, WmuT, 512, 32);
  transpose_f16_kernel<<<dim3(16, 8, 8), blk, 0, stream>>>(Wv0, Wv0T, 512, 256);
  transpose_f16_kernel<<<dim3(8, 8, 8), blk, 0, stream>>>(Wv1, Wv1T, 256, 256);
  transpose_split_kernel<<<dim3(16, 16, 1), blk, 0, stream>>>(Ww0, Ww0Thi, Ww0Tlo, 512, 512);
  transpose_split_kernel<<<dim3(16, 16, 1), blk, 0, stream>>>(Ww1, Ww1Thi, Ww1Tlo, 512, 512);

  // policy chain (grouped over experts; L1 concat-N shares the A tile)
  for (int e0 = 0; e0 < 8; e0 += eg) {
    gemm2_kernel<128, 128, 64, 64, 0><<<128 * 4 * eg, blk, 0, stream>>>(
        x16, Wp0T + (size_t)e0 * 512 * 512, bp0 + e0 * 512, BIG1,
        512, 0, sBD, 128, 4 * eg, 9);
    gemm2_kernel<128, 128, 64, 64, 0><<<128 * 4 * eg, blk, 0, stream>>>(
        BIG1, Wp1T + (size_t)e0 * 512 * 512, bp1 + e0 * 512, BIG2,
        512, sBD, sBD, 128, 4, 9);
    gemm2_kernel<128, 32, 32, 32, 1><<<128 * eg, blk, 0, stream>>>(
        BIG2, WmuT + (size_t)e0 * 32 * 512, bmu + e0 * 32,
        out_actions + (size_t)e0 * 16384 * 32,
        512, sBD, 16384LL * 32, 128, 1, 5);
  }

  // value chain (grouped over experts; L1 concat-N)
  for (int e0 = 0; e0 < 8; e0 += eg_v) {
    gemm2_kernel<128, 128, 64, 64, 0><<<128 * 2 * eg_v, blk, 0, stream>>>(
        x16, Wv0T + (size_t)e0 * 256 * 512, bv0 + e0 * 256, VB1,
        512, 0, sBH, 128, 2 * eg_v, 8);
    gemm2_kernel<128, 128, 64, 64, 0><<<128 * 2 * eg_v, blk, 0, stream>>>(
        VB1, Wv1T + (size_t)e0 * 256 * 256, bv1 + e0 * 256, VB2,
        256, sBH, sBH, 128, 2, 8);
    values_kernel<<<eg_v * 4096, blk, 0, stream>>>((const f16*)VB2, Wv, bv, valuesBuf, e0);
  }

  // gating network (fp16x2 split, ~f32 accuracy), then softmax/sample/gather
  gemm_gate_kernel<<<512, blk, 0, stream>>>(
      x16, xlo, Ww0Thi, Ww0Tlo, bw0, U1hi, U1lo, nullptr, 16384, 512, 512, 0);
  gemm_gate_kernel<<<512, blk, 0, stream>>>(
      U1hi, U1lo, Ww1Thi, Ww1Tlo, bw1, nullptr, nullptr, U2, 16384, 512, 512, 1);
  gating_out_kernel<<<4096, blk, 0, stream>>>(U2, Wwo, bwo, valuesBuf, out_w, out_v);
}